// Round 10
// baseline (200.889 us; speedup 1.0000x reference)
//
#include <hip/hip_runtime.h>
#include <cstdint>
#include <cstddef>

// (B,H,L,D,k) = (4,1,2048,512,4), SHIFTS = {1,2,4}
// Folded: out[(b,l,j),d] = sum_c v[c]*Qj[c,d]               (diff, K=512)
//                        + sum_{si,c} silu(v[c]*W[j,(c-s)%512]) * Psilu[si,c,d]  (K=1536)
// v = x[b,l-1] for j<3, x[b,l] for j==3.
// Round 13 (= R12 resubmit; R12 bench died to container infra, kernel never ran).
// The last untested cell {multi-block x zero-conflict x counted-vmcnt}:
// gemm = R8's 128x128 / BK=32 / 4-wave kernel (0-conflict 64-line x 128B layout,
// verified R8: SQ_LDS_BANK_CONFLICT 8.39M -> 0) with A,B as 3-slot rings
// (48 KB -> 3 blocks/CU) and ONE barrier + counted vmcnt(4) per step: tile T+2
// staged while T computes; never drain-0 until the tail.
// Prep (fused conv+GS+build_B) = round-3 known-good.
#define D_DIM 512
#define L_DIM 2048
#define KB_DIM 2048    // 512 diff + 3*512 silu
#define KS_DIM 1536
#define NROWS_X 2049   // per-b rows in XbfZ; row 0 is zeros (the l=-1 pad)
#define M_TOT 32768

typedef __bf16 bf16x8 __attribute__((ext_vector_type(8)));
typedef float  f32x4  __attribute__((ext_vector_type(4)));

__device__ __forceinline__ unsigned f2bf(float f) {
  unsigned u = __float_as_uint(f);
  u += 0x7FFF + ((u >> 16) & 1);   // RNE
  return u >> 16;
}
__device__ __forceinline__ float bf2f(unsigned short u) {
  return __uint_as_float(((unsigned)u) << 16);
}
__device__ __forceinline__ void gld_lds16(const void* g, void* l) {
  __builtin_amdgcn_global_load_lds((const __attribute__((address_space(1))) void*)g,
                                   (__attribute__((address_space(3))) void*)l,
                                   16, 0, 0);
}

// ---------------- fused prepass: conv(x)->XbfZ + GS silu rows  AND  build_B ----------
// grid 2304 x 256: blocks [0,2048) = conv/GS path (4 x-rows each);
//                  blocks [2048,2304) = build_B path (Ball).
__global__ __launch_bounds__(256) void prep(
    const float* __restrict__ x, const float* __restrict__ W, const float* __restrict__ P,
    unsigned short* __restrict__ XbfZ, unsigned short* __restrict__ Ball,
    unsigned short* __restrict__ GS, int doGS) {
  __shared__ unsigned short WtabL[6144];   // [j*3+si][c] bf16(W[j,(c-s)&511])
  const int tid = threadIdx.x;

  if (blockIdx.x < 2048) {
    // ---------------- conv + GS path ----------------
    for (int i = tid; i < 6144; i += 256) {
      const int c = i & 511; const int rest = i >> 9;   // rest = j*3+si
      const int si = rest % 3; const int jj = rest / 3;
      WtabL[i] = (unsigned short)f2bf(W[jj * 512 + ((c - (1 << si)) & 511)]);
    }
    __syncthreads();

    const int r = tid >> 6, lane = tid & 63;
    const int gr = blockIdx.x * 4 + r;          // x-row index 0..8191
    const int b = gr >> 11, l = gr & 2047;

    // load x[b,l] (8 floats per lane), convert to bf16
    const float4* xr = reinterpret_cast<const float4*>(x) + ((size_t)(b * L_DIM + l)) * 128 + lane * 2;
    const float4 v0 = xr[0], v1 = xr[1];
    union U { uint4 q; unsigned short s[8]; };
    U va;
    va.q.x = f2bf(v0.x) | (f2bf(v0.y) << 16);
    va.q.y = f2bf(v0.z) | (f2bf(v0.w) << 16);
    va.q.z = f2bf(v1.x) | (f2bf(v1.y) << 16);
    va.q.w = f2bf(v1.z) | (f2bf(v1.w) << 16);
    *reinterpret_cast<uint4*>(XbfZ + ((size_t)(b * NROWS_X + l + 1)) * 512 + lane * 8) = va.q;

    if (doGS) {
      #pragma unroll
      for (int j = 0; j < 4; ++j) {
        // dest GS row: j<3 -> (j,b,l+1) (only if l+1<2048); j==3 -> (3,b,l)
        const int lam = (j < 3) ? (l + 1) : l;
        const bool wr = (j == 3) || (l < 2047);
        unsigned short* o = GS + ((size_t)((j * 4 + b) * L_DIM + lam)) * KS_DIM + lane * 8;
        #pragma unroll
        for (int si = 0; si < 3; ++si) {
          U wa;
          wa.q = *reinterpret_cast<const uint4*>(&WtabL[(j * 3 + si) * 512 + lane * 8]);
          unsigned res[4];
          #pragma unroll
          for (int e = 0; e < 4; ++e) {
            float s0 = bf2f(va.s[2 * e])     * bf2f(wa.s[2 * e]);
            float s1 = bf2f(va.s[2 * e + 1]) * bf2f(wa.s[2 * e + 1]);
            float g0 = s0 * __builtin_amdgcn_rcpf(1.f + __expf(-s0));
            float g1 = s1 * __builtin_amdgcn_rcpf(1.f + __expf(-s1));
            res[e] = f2bf(g0) | (f2bf(g1) << 16);
          }
          if (wr) {
            uint4 ov = {res[0], res[1], res[2], res[3]};
            *reinterpret_cast<uint4*>(o + si * 512) = ov;
          }
        }
      }
    }
    // per-b zero rows (row 0 of XbfZ, lambda=0 GS rows for j<3): one x-row (l==2047) per b
    if (l == 2047) {
      const uint4 z = {0u, 0u, 0u, 0u};
      *reinterpret_cast<uint4*>(XbfZ + ((size_t)(b * NROWS_X)) * 512 + lane * 8) = z;
      if (doGS) {
        #pragma unroll
        for (int j = 0; j < 3; ++j)
          #pragma unroll
          for (int si = 0; si < 3; ++si)
            *reinterpret_cast<uint4*>(GS + ((size_t)((j * 4 + b) * L_DIM)) * KS_DIM + si * 512 + lane * 8) = z;
      }
    }
    return;
  }

  // ---------------- build_B path (Ball) ----------------
  const int bx = blockIdx.x - 2048;      // 0..255
  const int j = bx >> 6, dt = (bx >> 3) & 7, ct = bx & 7;
  const int d = dt * 64 + (tid & 63);
  const int cbase = ct * 64 + (tid >> 6) * 16;
  unsigned short bufd[16];
  unsigned short bufs[3][16];
  #pragma unroll
  for (int cc = 0; cc < 16; ++cc) {
    const int c = cbase + cc;
    float qd = 0.f;
    #pragma unroll
    for (int si = 0; si < 3; ++si) {
      const int s = 1 << si;
      const int cm = (c - s) & 511, cp = (c + s) & 511;
      qd += W[j * 512 + cm] * P[((size_t)(2 * si) * 512 + c) * 512 + d]
          - W[j * 512 + cp] * P[((size_t)(2 * si) * 512 + cp) * 512 + d];
      bufs[si][cc] = (unsigned short)f2bf(P[((size_t)(2 * si + 1) * 512 + c) * 512 + d]);
    }
    bufd[cc] = (unsigned short)f2bf(qd);
  }
  unsigned short* row = Ball + (size_t)(j * 512 + d) * KB_DIM;
  *reinterpret_cast<uint4*>(&row[cbase])     = *reinterpret_cast<uint4*>(&bufd[0]);
  *reinterpret_cast<uint4*>(&row[cbase + 8]) = *reinterpret_cast<uint4*>(&bufd[8]);
  #pragma unroll
  for (int si = 0; si < 3; ++si) {
    *reinterpret_cast<uint4*>(&row[512 + si * 512 + cbase])     = *reinterpret_cast<uint4*>(&bufs[si][0]);
    *reinterpret_cast<uint4*>(&row[512 + si * 512 + cbase + 8]) = *reinterpret_cast<uint4*>(&bufs[si][8]);
  }
}

// ---------------- main GEMM: 128x128, BK=32, 4 waves, 3-slot rings, vmcnt(4) --------
// LDS buffer = 64 lines x 128 B (8 slots of 16 B). Line i holds:
//   row i,    chunks 0..3  -> c' = chunk
//   row i+64, chunks 0..3  -> c' = chunk + 4
// slot(line, c') = line*8 + (c' ^ (line&7)).
// Fragment read: spos = (quad + wHalf*4) ^ (l16&7) -> bijective over each
// consecutive-8-lane phase (zero-conflict condition; VERIFIED 0 in R8 counters).
// Schedule (1 barrier/step): step T stages tile T+2 -> slot (T+2)%3 (readers of
// that slot sealed by end-of-(T-1) barrier); reads slot T%3; VMW(4) leaves tile
// T+2's 4 loads in flight (each wave waits its OWN loads; barrier then makes all
// waves' tile-(T+1) data globally visible). VMW(0) only at T==62.
#define VMW(N) asm volatile("s_waitcnt vmcnt(" #N ")" ::: "memory")

__global__ __launch_bounds__(256, 3) void gemm128r(
    const unsigned short* __restrict__ XbfZ, const unsigned short* __restrict__ GS,
    const unsigned short* __restrict__ Ball, const float* __restrict__ bias,
    float* __restrict__ out) {
  __shared__ alignas(16) unsigned short A_lds[3][4096];
  __shared__ alignas(16) unsigned short B_lds[3][4096];

  const int tid = threadIdx.x;
  // Bijective XCD swizzle (1024 blocks, 8 XCDs): XCD x gets wids x*128..x*128+127.
  // 4 consecutive wids share one mtile's A panel (L2 reuse); j fixed per XCD pair.
  const int bid = blockIdx.x;
  const int wid = (bid & 7) * 128 + (bid >> 3);
  const int mtile = wid >> 2;            // 0..255
  const int ntile = wid & 3;             // 0..3
  const int j  = mtile >> 6;
  const int b  = (mtile >> 4) & 3;
  const int l0 = (mtile & 15) * 128;
  const int n0 = ntile * 128;
  const size_t mbase = (size_t)((j * 4 + b) * L_DIM + l0);

  // ---- staging geometry: thread covers slots tid and tid+256.
  // slot s: line = s>>3, spos = s&7, c' = spos ^ (line&7), chunk = c'&3,
  // row = line + 64*(c'>=4). Slot tid+256: line+32, same c' -> row+32, same chunk.
  const int line = tid >> 3;             // 0..31
  const int spos = tid & 7;
  const int cp   = spos ^ (line & 7);    // c' 0..7
  const int sc   = cp & 3;               // chunk 0..3
  const int srow = line + ((cp >> 2) << 6);   // +64 for upper half
  const unsigned short* pXd = XbfZ + ((size_t)(b * NROWS_X + (j == 3) + l0 + srow)) * 512 + sc * 8;
  const unsigned short* pGS = GS + (mbase + srow) * (size_t)KS_DIM + sc * 8;
  const unsigned short* pB  = Ball + ((size_t)(j * 512 + n0 + srow)) * KB_DIM + sc * 8;
  const int ldsSlot = tid * 8;           // shorts; second slot at +2048

  auto stageA = [&](int TT, int bufi) {  // 2 glds (rows srow, srow+32)
    unsigned short* dst = &A_lds[bufi][ldsSlot];
    if (TT < 16) {
      const unsigned short* s = pXd + TT * 32;
      gld_lds16(s, dst);
      gld_lds16(s + 32 * 512, dst + 2048);
    } else {
      const unsigned short* s = pGS + (TT - 16) * 32;
      gld_lds16(s, dst);
      gld_lds16(s + 32 * KS_DIM, dst + 2048);
    }
  };
  auto stageB = [&](int TT, int bufi) {  // 2 glds
    const unsigned short* s = pB + TT * 32;
    unsigned short* dst = &B_lds[bufi][ldsSlot];
    gld_lds16(s, dst);
    gld_lds16(s + 32 * KB_DIM, dst + 2048);
  };

  // ---- MFMA frag geometry: 4 waves 2(M) x 2(N); per-wave output 64x64 ----
  const int lane = tid & 63, wv = tid >> 6;
  const int wm = wv >> 1, wn = wv & 1;
  const int l16 = lane & 15, quad = lane >> 4;
  const int rpA = ((quad + wm * 4) ^ (l16 & 7)) * 8;   // A half = wm
  const int rpB = ((quad + wn * 4) ^ (l16 & 7)) * 8;   // B half = wn
  int aOff[4], bOff[4];
  #pragma unroll
  for (int mf = 0; mf < 4; ++mf) aOff[mf] = (mf * 16 + l16) * 64 + rpA;
  #pragma unroll
  for (int nf = 0; nf < 4; ++nf) bOff[nf] = (nf * 16 + l16) * 64 + rpB;

  f32x4 acc[4][4];
  #pragma unroll
  for (int i = 0; i < 4; ++i)
    #pragma unroll
    for (int n = 0; n < 4; ++n)
      acc[i][n] = f32x4{0.f, 0.f, 0.f, 0.f};

  bf16x8 a[4], bf[4];

  // ---- prologue: stage tiles 0,1; wait tile 0 (tile 1's 4 loads stay in flight) ----
  stageA(0, 0); stageB(0, 0);
  stageA(1, 1); stageB(1, 1);
  VMW(4);
  asm volatile("s_barrier" ::: "memory");

  // Steady state (step T, cur = T%3): one barrier per step, counted vmcnt.
  int cur = 0;
  for (int T = 0; T < 64; ++T) {
    const int rs = (cur >= 1) ? (cur - 1) : 2;   // (T+2)%3
    if (T + 2 < 64) { stageA(T + 2, rs); stageB(T + 2, rs); }
    const unsigned short* Ac = A_lds[cur];
    const unsigned short* Bc = B_lds[cur];
    #pragma unroll
    for (int mf = 0; mf < 4; ++mf)
      a[mf] = __builtin_bit_cast(bf16x8, *reinterpret_cast<const uint4*>(&Ac[aOff[mf]]));
    #pragma unroll
    for (int nf = 0; nf < 4; ++nf)
      bf[nf] = __builtin_bit_cast(bf16x8, *reinterpret_cast<const uint4*>(&Bc[bOff[nf]]));
    __builtin_amdgcn_s_setprio(1);
    #pragma unroll
    for (int mf = 0; mf < 4; ++mf)
      #pragma unroll
      for (int nf = 0; nf < 4; ++nf)
        acc[mf][nf] = __builtin_amdgcn_mfma_f32_16x16x32_bf16(a[mf], bf[nf], acc[mf][nf], 0, 0, 0);
    __builtin_amdgcn_s_setprio(0);
    if (T < 62) {
      VMW(4);                                   // tile T+1 landed; T+2 in flight
      asm volatile("s_barrier" ::: "memory");
    } else if (T == 62) {
      VMW(0);                                   // tail: tile 63 must fully land
      asm volatile("s_barrier" ::: "memory");
    }
    cur = (cur >= 2) ? 0 : (cur + 1);
  }

  // ---- epilogue: C/D col = lane&15 (N), row = quad*4+reg (M) ----
  #pragma unroll
  for (int nf = 0; nf < 4; ++nf) {
    const int d = n0 + wn * 64 + nf * 16 + l16;
    const float bv = bias[d];
    #pragma unroll
    for (int mf = 0; mf < 4; ++mf) {
      const int lrow = l0 + wm * 64 + mf * 16 + quad * 4;
      #pragma unroll
      for (int rg = 0; rg < 4; ++rg) {
        out[((size_t)(b * L_DIM + lrow + rg) * 4 + j) * D_DIM + d] = acc[mf][nf][rg] + bv;
      }
    }
  }
}

// ---------------- fallback: fused kernel (used if ws too small) ----------------
__global__ __launch_bounds__(256, 2) void fused_gemm(
    const unsigned short* __restrict__ XbfZ, const unsigned short* __restrict__ Ball,
    const float* __restrict__ W, const float* __restrict__ bias,
    float* __restrict__ out) {
  __shared__ alignas(16) unsigned short Vt[2][4096];
  __shared__ alignas(16) unsigned short Bt[2][8192];
  __shared__ alignas(16) unsigned short At[128 * 40];
  __shared__ alignas(16) unsigned short Wr[3 * 512];

  const int tid = threadIdx.x;
  const int nt = blockIdx.x & 1;
  const int mt = blockIdx.x >> 1;
  const int j  = mt >> 6;
  const int b  = (mt >> 4) & 3;
  const int lt = mt & 15;
  const int l0 = lt * 128;
  const int n0 = nt * 256;
  const int base_l = l0 - ((j == 3) ? 0 : 1);

  #pragma unroll
  for (int i = 0; i < 6; ++i) {
    const int idx = tid + i * 256;
    const int si = idx >> 9, c = idx & 511, s = 1 << si;
    Wr[idx] = (unsigned short)f2bf(W[j * 512 + ((c - s) & 511)]);
  }

  const int lane = tid & 63, wv = tid >> 6;
  const int qv = (lane & 3) ^ ((lane >> 4) & 3);
  const int rsub = lane >> 2;
  const unsigned short* gA0 = XbfZ + ((size_t)(b * NROWS_X + 1 + base_l + (wv * 2) * 16 + rsub)) * 512 + qv * 8;
  const unsigned short* gA1 = gA0 + (size_t)16 * 512;
  const unsigned short* gB[4];
  #pragma unroll
  for (int pi = 0; pi < 4; ++pi)
    gB[pi] = Ball + (size_t)(j * 512 + n0 + (wv * 4 + pi) * 16 + rsub) * KB_DIM + qv * 8;
  const int vOff0 = wv * 1024 + lane * 8;
  const int bOff0 = wv * 2048 + lane * 8;

  const int am = tid >> 1;
  const int akh = (tid & 1) * 16;
  const int ch0 = (tid & 1) * 2;
  const int sswz = (am >> 2) & 3;
  unsigned short* aDst = &At[am * 40 + akh];

  const int l16 = lane & 15, quad = lane >> 4;
  const int wm = wv >> 1, wn = wv & 1;
  const int fsw = (l16 >> 2) & 3;
  const int aVoff = (wm * 64 + l16) * 32 + ((quad ^ fsw)) * 8;
  const int aSoff = (wm * 64 + l16) * 40 + quad * 8;
  const int bOffF = (wn * 128 + l16) * 32 + ((quad ^ fsw)) * 8;

  f32x4 acc[4][8];
  #pragma unroll
  for (int i = 0; i < 4; ++i)
    #pragma unroll
    for (int n = 0; n < 8; ++n)
      acc[i][n] = f32x4{0.f, 0.f, 0.f, 0.f};

  {
    gld_lds16(gA0, &Vt[0][vOff0]);
    gld_lds16(gA1, &Vt[0][vOff0 + 512]);
    #pragma unroll
    for (int pi = 0; pi < 4; ++pi)
      gld_lds16(gB[pi], &Bt[0][bOff0 + pi * 512]);
  }

  for (int it = 0; it < 64; ++it) {
    const int buf = it & 1;
    const int kk0 = it * 32;
    const int gi = kk0 >> 9;

    __syncthreads();

    if (it + 1 < 64) {
      const int nk = kk0 + 32;
      const int nv = nk & 511;
      gld_lds16(gA0 + nv, &Vt[buf ^ 1][vOff0]);
      gld_lds16(gA1 + nv, &Vt[buf ^ 1][vOff0 + 512]);
      #pragma unroll
      for (int pi = 0; pi < 4; ++pi)
        gld_lds16(gB[pi] + nk, &Bt[buf ^ 1][bOff0 + pi * 512]);
    }

    bf16x8 af[4], bfr[8];
    if (gi == 0) {
      #pragma unroll
      for (int mi = 0; mi < 4; ++mi) {
        uint4 r = *reinterpret_cast<const uint4*>(&Vt[buf][aVoff + mi * 512]);
        af[mi] = __builtin_bit_cast(bf16x8, r);
      }
    } else {
      const int si = gi - 1;
      const int ccbase = (kk0 & 511) + akh;
      uint4 v0 = *reinterpret_cast<const uint4*>(&Vt[buf][(am * 4 + ((ch0)     ^ sswz)) * 8]);
      uint4 v1 = *reinterpret_cast<const uint4*>(&Vt[buf][(am * 4 + ((ch0 + 1) ^ sswz)) * 8]);
      uint4 w0 = *reinterpret_cast<const uint4*>(&Wr[si * 512 + ccbase]);
      uint4 w1 = *reinterpret_cast<const uint4*>(&Wr[si * 512 + ccbase + 8]);
      union U { uint4 q[2]; unsigned short s[16]; };
      U va, wa; va.q[0] = v0; va.q[1] = v1; wa.q[0] = w0; wa.q[1] = w1;
      unsigned res[8];
      #pragma unroll
      for (int e = 0; e < 8; ++e) {
        float s0 = bf2f(va.s[2 * e])     * bf2f(wa.s[2 * e]);
        float s1 = bf2f(va.s[2 * e + 1]) * bf2f(wa.s[2 * e + 1]);
        float g0 = s0 * __builtin_amdgcn_rcpf(1.f + __expf(-s0));
        float g1 = s1 * __builtin_amdgcn_rcpf(1.f + __expf(-s1));
        res[e] = f2bf(g0) | (f2bf(g1) << 16);
      }
      uint4 o0 = {res[0], res[1], res[2], res[3]};
      uint4 o1 = {res[4], res[5], res[6], res[7]};
      *reinterpret_cast<uint4*>(aDst) = o0;
      *reinterpret_cast<uint4*>(aDst + 8) = o1;
      __syncthreads();
      #pragma unroll
      for (int mi = 0; mi < 4; ++mi) {
        uint4 r = *reinterpret_cast<const uint4*>(&At[aSoff + mi * 640]);
        af[mi] = __builtin_bit_cast(bf16x8, r);
      }
    }
    #pragma unroll
    for (int ni = 0; ni < 8; ++ni) {
      uint4 r = *reinterpret_cast<const uint4*>(&Bt[buf][bOffF + ni * 512]);
      bfr[ni] = __builtin_bit_cast(bf16x8, r);
    }
    #pragma unroll
    for (int mi = 0; mi < 4; ++mi)
      #pragma unroll
      for (int ni = 0; ni < 8; ++ni)
        acc[mi][ni] = __builtin_amdgcn_mfma_f32_16x16x32_bf16(af[mi], bfr[ni], acc[mi][ni], 0, 0, 0);
  }

  #pragma unroll
  for (int ni = 0; ni < 8; ++ni) {
    const int d = n0 + wn * 128 + ni * 16 + l16;
    const float bv = bias[d];
    #pragma unroll
    for (int mi = 0; mi < 4; ++mi) {
      const int lrow = l0 + wm * 64 + mi * 16 + quad * 4;
      #pragma unroll
      for (int rg = 0; rg < 4; ++rg) {
        out[((size_t)(b * L_DIM + lrow + rg) * 4 + j) * D_DIM + d] = acc[mi][ni][rg] + bv;
      }
    }
  }
}

extern "C" void kernel_launch(void* const* d_in, const int* in_sizes, int n_in,
                              void* d_out, int out_size, void* d_ws, size_t ws_size,
                              hipStream_t stream) {
  const float* x    = (const float*)d_in[0];  // (4,1,2048,512) fp32
  const float* W    = (const float*)d_in[1];  // (4,512) fp32
  const float* P    = (const float*)d_in[2];  // (3072,512) fp32
  const float* bias = (const float*)d_in[3];  // (512,) fp32
  float* out = (float*)d_out;                 // (4,1,8192,512) fp32

  unsigned short* XbfZ = (unsigned short*)d_ws;                       // 4*2049*512   = 4,196,352 shorts
  unsigned short* Ball = XbfZ + (size_t)4 * NROWS_X * 512;            // 4*512*2048   = 4,194,304
  unsigned short* GS   = Ball + (size_t)4 * 512 * KB_DIM + 6144;      // 32768*1536   = 50,331,648
  const size_t need_bytes =
      ((size_t)4 * NROWS_X * 512 + (size_t)4 * 512 * KB_DIM + 6144 +
       (size_t)M_TOT * KS_DIM) * 2;
  const bool primary = ws_size >= need_bytes;

  prep<<<2304, 256, 0, stream>>>(x, W, P, XbfZ, Ball, GS, primary ? 1 : 0);
  if (primary) {
    gemm128r<<<dim3(1024), dim3(256), 0, stream>>>(XbfZ, GS, Ball, bias, out);
  } else {
    fused_gemm<<<512, 256, 0, stream>>>(XbfZ, Ball, W, bias, out);
  }
}

// Round 11
// 175.393 us; speedup vs baseline: 1.1454x; 1.1454x over previous
//
#include <hip/hip_runtime.h>
#include <cstdint>
#include <cstddef>

// (B,H,L,D,k) = (4,1,2048,512,4), SHIFTS = {1,2,4}
// Folded: out[(b,l,j),d] = sum_c v[c]*Qj[c,d]               (diff, K=512)
//                        + sum_{si,c} silu(v[c]*W[j,(c-s)%512]) * Psilu[si,c,d]  (K=1536)
// v = x[b,l-1] for j<3, x[b,l] for j==3.
// FINAL (round 14) = restore of the measured global best (round-3 config, 175.6 us):
// (1) fused prepass (conv+GS+build_B in one launch, per-block LDS Wtab);
// (2) gemm = 256x256 tile, BK=64, 8 waves, 16x16x32 MFMA, conflict-free chunk-XOR
//     LDS swizzle (verified 0 conflicts), minimal-hazard 2-barrier/K-tile schedule,
//     counted vmcnt(4) (B(T+2) stays in flight; drain-0 only at the tail),
//     bijective XCD block swizzle.
// Exploration summary (rounds 4-10): schedule variants (8-barrier, c-major in-reg
// silu, 3-deep ring, 32x32 MFMA), occupancy variants (4-wave 128^2 at 3-4 blk/CU),
// and counted-vmcnt multi-block all measured equal or worse (82 -> 92-116 us);
// the 81.5 us gemm / 33% MfmaUtil plateau is schedule-invariant at this shape.
#define D_DIM 512
#define L_DIM 2048
#define KB_DIM 2048    // 512 diff + 3*512 silu
#define KS_DIM 1536
#define NROWS_X 2049   // per-b rows in XbfZ; row 0 is zeros (the l=-1 pad)
#define M_TOT 32768

typedef __bf16 bf16x8 __attribute__((ext_vector_type(8)));
typedef float  f32x4  __attribute__((ext_vector_type(4)));

__device__ __forceinline__ unsigned f2bf(float f) {
  unsigned u = __float_as_uint(f);
  u += 0x7FFF + ((u >> 16) & 1);   // RNE
  return u >> 16;
}
__device__ __forceinline__ float bf2f(unsigned short u) {
  return __uint_as_float(((unsigned)u) << 16);
}
__device__ __forceinline__ void gld_lds16(const void* g, void* l) {
  __builtin_amdgcn_global_load_lds((const __attribute__((address_space(1))) void*)g,
                                   (__attribute__((address_space(3))) void*)l,
                                   16, 0, 0);
}

// ---------------- fused prepass: conv(x)->XbfZ + GS silu rows  AND  build_B ----------
// grid 2304 x 256: blocks [0,2048) = conv/GS path (4 x-rows each);
//                  blocks [2048,2304) = build_B path (Ball).
__global__ __launch_bounds__(256) void prep(
    const float* __restrict__ x, const float* __restrict__ W, const float* __restrict__ P,
    unsigned short* __restrict__ XbfZ, unsigned short* __restrict__ Ball,
    unsigned short* __restrict__ GS, int doGS) {
  __shared__ unsigned short WtabL[6144];   // [j*3+si][c] bf16(W[j,(c-s)&511])
  const int tid = threadIdx.x;

  if (blockIdx.x < 2048) {
    // ---------------- conv + GS path ----------------
    for (int i = tid; i < 6144; i += 256) {
      const int c = i & 511; const int rest = i >> 9;   // rest = j*3+si
      const int si = rest % 3; const int jj = rest / 3;
      WtabL[i] = (unsigned short)f2bf(W[jj * 512 + ((c - (1 << si)) & 511)]);
    }
    __syncthreads();

    const int r = tid >> 6, lane = tid & 63;
    const int gr = blockIdx.x * 4 + r;          // x-row index 0..8191
    const int b = gr >> 11, l = gr & 2047;

    // load x[b,l] (8 floats per lane), convert to bf16
    const float4* xr = reinterpret_cast<const float4*>(x) + ((size_t)(b * L_DIM + l)) * 128 + lane * 2;
    const float4 v0 = xr[0], v1 = xr[1];
    union U { uint4 q; unsigned short s[8]; };
    U va;
    va.q.x = f2bf(v0.x) | (f2bf(v0.y) << 16);
    va.q.y = f2bf(v0.z) | (f2bf(v0.w) << 16);
    va.q.z = f2bf(v1.x) | (f2bf(v1.y) << 16);
    va.q.w = f2bf(v1.z) | (f2bf(v1.w) << 16);
    *reinterpret_cast<uint4*>(XbfZ + ((size_t)(b * NROWS_X + l + 1)) * 512 + lane * 8) = va.q;

    if (doGS) {
      #pragma unroll
      for (int j = 0; j < 4; ++j) {
        // dest GS row: j<3 -> (j,b,l+1) (only if l+1<2048); j==3 -> (3,b,l)
        const int lam = (j < 3) ? (l + 1) : l;
        const bool wr = (j == 3) || (l < 2047);
        unsigned short* o = GS + ((size_t)((j * 4 + b) * L_DIM + lam)) * KS_DIM + lane * 8;
        #pragma unroll
        for (int si = 0; si < 3; ++si) {
          U wa;
          wa.q = *reinterpret_cast<const uint4*>(&WtabL[(j * 3 + si) * 512 + lane * 8]);
          unsigned res[4];
          #pragma unroll
          for (int e = 0; e < 4; ++e) {
            float s0 = bf2f(va.s[2 * e])     * bf2f(wa.s[2 * e]);
            float s1 = bf2f(va.s[2 * e + 1]) * bf2f(wa.s[2 * e + 1]);
            float g0 = s0 * __builtin_amdgcn_rcpf(1.f + __expf(-s0));
            float g1 = s1 * __builtin_amdgcn_rcpf(1.f + __expf(-s1));
            res[e] = f2bf(g0) | (f2bf(g1) << 16);
          }
          if (wr) {
            uint4 ov = {res[0], res[1], res[2], res[3]};
            *reinterpret_cast<uint4*>(o + si * 512) = ov;
          }
        }
      }
    }
    // per-b zero rows (row 0 of XbfZ, lambda=0 GS rows for j<3): one x-row (l==2047) per b
    if (l == 2047) {
      const uint4 z = {0u, 0u, 0u, 0u};
      *reinterpret_cast<uint4*>(XbfZ + ((size_t)(b * NROWS_X)) * 512 + lane * 8) = z;
      if (doGS) {
        #pragma unroll
        for (int j = 0; j < 3; ++j)
          #pragma unroll
          for (int si = 0; si < 3; ++si)
            *reinterpret_cast<uint4*>(GS + ((size_t)((j * 4 + b) * L_DIM)) * KS_DIM + si * 512 + lane * 8) = z;
      }
    }
    return;
  }

  // ---------------- build_B path (Ball) ----------------
  const int bx = blockIdx.x - 2048;      // 0..255
  const int j = bx >> 6, dt = (bx >> 3) & 7, ct = bx & 7;
  const int d = dt * 64 + (tid & 63);
  const int cbase = ct * 64 + (tid >> 6) * 16;
  unsigned short bufd[16];
  unsigned short bufs[3][16];
  #pragma unroll
  for (int cc = 0; cc < 16; ++cc) {
    const int c = cbase + cc;
    float qd = 0.f;
    #pragma unroll
    for (int si = 0; si < 3; ++si) {
      const int s = 1 << si;
      const int cm = (c - s) & 511, cp = (c + s) & 511;
      qd += W[j * 512 + cm] * P[((size_t)(2 * si) * 512 + c) * 512 + d]
          - W[j * 512 + cp] * P[((size_t)(2 * si) * 512 + cp) * 512 + d];
      bufs[si][cc] = (unsigned short)f2bf(P[((size_t)(2 * si + 1) * 512 + c) * 512 + d]);
    }
    bufd[cc] = (unsigned short)f2bf(qd);
  }
  unsigned short* row = Ball + (size_t)(j * 512 + d) * KB_DIM;
  *reinterpret_cast<uint4*>(&row[cbase])     = *reinterpret_cast<uint4*>(&bufd[0]);
  *reinterpret_cast<uint4*>(&row[cbase + 8]) = *reinterpret_cast<uint4*>(&bufd[8]);
  #pragma unroll
  for (int si = 0; si < 3; ++si) {
    *reinterpret_cast<uint4*>(&row[512 + si * 512 + cbase])     = *reinterpret_cast<uint4*>(&bufs[si][0]);
    *reinterpret_cast<uint4*>(&row[512 + si * 512 + cbase + 8]) = *reinterpret_cast<uint4*>(&bufs[si][8]);
  }
}

// ---------------- main GEMM: 256x256, BK=64, 8 waves, 16x16x32 MFMA, 2 barriers/tile --
#define BARR asm volatile("s_barrier" ::: "memory")
#define VMW(N) asm volatile("s_waitcnt vmcnt(" #N ")" ::: "memory")

#define READ_A(MH, BUF) do { \
  _Pragma("unroll") \
  for (int mf = 0; mf < 4; ++mf) { \
    a[mf][0] = __builtin_bit_cast(bf16x8, *reinterpret_cast<const uint4*>(&A_lds[BUF][aRow[mf] + (MH)*4096 + p0])); \
    a[mf][1] = __builtin_bit_cast(bf16x8, *reinterpret_cast<const uint4*>(&A_lds[BUF][aRow[mf] + (MH)*4096 + p1])); \
  } } while (0)

#define READ_B(NH, BUF, BB) do { \
  _Pragma("unroll") \
  for (int nf = 0; nf < 2; ++nf) { \
    BB[nf][0] = __builtin_bit_cast(bf16x8, *reinterpret_cast<const uint4*>(&B_lds[BUF][bRow[nf] + (NH)*2048 + p0])); \
    BB[nf][1] = __builtin_bit_cast(bf16x8, *reinterpret_cast<const uint4*>(&B_lds[BUF][bRow[nf] + (NH)*2048 + p1])); \
  } } while (0)

#define MFMA_Q(MH, NH, BB) do { \
  _Pragma("unroll") \
  for (int mf = 0; mf < 4; ++mf) { \
    _Pragma("unroll") \
    for (int nf = 0; nf < 2; ++nf) { \
      acc[(MH)*4+mf][(NH)*2+nf] = __builtin_amdgcn_mfma_f32_16x16x32_bf16(a[mf][0], BB[nf][0], acc[(MH)*4+mf][(NH)*2+nf], 0, 0, 0); \
      acc[(MH)*4+mf][(NH)*2+nf] = __builtin_amdgcn_mfma_f32_16x16x32_bf16(a[mf][1], BB[nf][1], acc[(MH)*4+mf][(NH)*2+nf], 0, 0, 0); \
    } } } while (0)

__global__ __launch_bounds__(512, 2) void gemm8(
    const unsigned short* __restrict__ XbfZ, const unsigned short* __restrict__ GS,
    const unsigned short* __restrict__ Ball, const float* __restrict__ bias,
    float* __restrict__ out) {
  // Each buffer: 256 rows x 64 k x bf16 = 32 KB (row = 128 B = 8 chunks of 16 B).
  // Chunk XOR swizzle: chunk c of row r stored at pos p = c ^ (r&7).
  __shared__ alignas(16) unsigned short A_lds[2][16384];
  __shared__ alignas(16) unsigned short B_lds[2][16384];

  const int tid = threadIdx.x;
  // Bijective XCD swizzle (256 blocks, 8 XCDs): XCD x gets wids x*32..x*32+31.
  const int bid = blockIdx.x;
  const int wid = (bid & 7) * 32 + (bid >> 3);
  const int mtile = wid >> 1;            // 0..127
  const int ntile = wid & 1;             // 0..1
  const int j  = mtile >> 5;
  const int b  = (mtile >> 3) & 3;
  const int l0 = (mtile & 7) * 256;
  const int n0 = ntile * 256;
  const size_t mbase = (size_t)((j * 4 + b) * L_DIM + l0);

  // ---- staging geometry: thread covers slots tid and tid+512 of each half-tile.
  // slot s: row = s>>3, pos = s&7; global chunk c = pos ^ (row&7) (same for both slots).
  const int srow = tid >> 3;             // 0..63
  const int c8   = (tid & 7) ^ (srow & 7);
  const unsigned short* pXd = XbfZ + ((size_t)(b * NROWS_X + (j == 3) + l0 + srow)) * 512 + c8 * 8;
  const unsigned short* pGS = GS + (mbase + srow) * (size_t)KS_DIM + c8 * 8;
  const unsigned short* pB  = Ball + ((size_t)(j * 512 + n0 + srow)) * KB_DIM + c8 * 8;
  const int ldsSlot = tid * 8;           // shorts; second slot at +4096

  auto stageA = [&](int TT, int h, int bufi) {
    unsigned short* dst = &A_lds[bufi][h * 8192 + ldsSlot];
    if (TT < 8) {
      const unsigned short* s = pXd + (size_t)h * 128 * 512 + TT * 64;
      gld_lds16(s, dst);
      gld_lds16(s + 64 * 512, dst + 4096);
    } else {
      const unsigned short* s = pGS + (size_t)h * 128 * KS_DIM + (TT - 8) * 64;
      gld_lds16(s, dst);
      gld_lds16(s + 64 * KS_DIM, dst + 4096);
    }
  };
  auto stageB = [&](int TT, int h, int bufi) {
    const unsigned short* s = pB + (size_t)h * 128 * KB_DIM + TT * 64;
    unsigned short* dst = &B_lds[bufi][h * 8192 + ldsSlot];
    gld_lds16(s, dst);
    gld_lds16(s + 64 * KB_DIM, dst + 4096);
  };

  // ---- MFMA frag geometry: 8 waves 2(M) x 4(N); per-wave output 128x64 ----
  const int lane = tid & 63, wv = tid >> 6;
  const int wm = wv >> 2, wn = wv & 3;
  const int l16 = lane & 15, quad = lane >> 4;
  const int p0 = ((quad)     ^ (l16 & 7)) * 8;   // k-chunk ks=0 (after XOR swizzle)
  const int p1 = ((quad + 4) ^ (l16 & 7)) * 8;   // k-chunk ks=1
  int aRow[4], bRow[2];
  #pragma unroll
  for (int mf = 0; mf < 4; ++mf) aRow[mf] = (wm * 128 + mf * 16 + l16) * 64;
  #pragma unroll
  for (int nf = 0; nf < 2; ++nf) bRow[nf] = (wn * 64 + nf * 16 + l16) * 64;

  f32x4 acc[8][4];
  #pragma unroll
  for (int i = 0; i < 8; ++i)
    #pragma unroll
    for (int n = 0; n < 4; ++n)
      acc[i][n] = f32x4{0.f, 0.f, 0.f, 0.f};

  bf16x8 a[4][2], b0[2][2], b1[2][2];

  // ---- prologue: tile0 complete + B-halves of tile1 in flight (4 youngest) ----
  stageB(0, 0, 0); stageB(0, 1, 0);
  stageA(0, 0, 0); stageA(0, 1, 0);
  stageB(1, 0, 1); stageB(1, 1, 1);
  VMW(4);          // oldest 8 (= all of tile 0) landed; B(1) still in flight
  BARR;

  // Steady state (tile T, cur=T&1), 2 barriers per tile:
  //   ph0: stage A(T+1)->nxt ; read A-h0 + ALL B ; MFMA quadrants (0,0),(0,1)
  //        BARR   [all waves' B-reads reg-resident (MFMA forced lgkm drain)
  //                before any stageB(T+2) write to cur]
  //   ph1: stage B(T+2)->cur ; read A-h1 ; MFMA quadrants (1,1),(1,0)
  //        VMW(4) [tile T+1 landed; B(T+2) = 4 youngest stays in flight] ; BARR
  for (int T = 0; T < 32; ++T) {
    const int cur = T & 1, nxt = cur ^ 1;
    // ---- phase 0 ----
    if (T + 1 < 32) { stageA(T + 1, 0, nxt); stageA(T + 1, 1, nxt); }
    READ_A(0, cur);
    READ_B(0, cur, b0);
    READ_B(1, cur, b1);
    __builtin_amdgcn_s_setprio(1);
    MFMA_Q(0, 0, b0);
    MFMA_Q(0, 1, b1);
    __builtin_amdgcn_s_setprio(0);
    BARR;
    // ---- phase 1 ----
    if (T + 2 < 32) { stageB(T + 2, 0, cur); stageB(T + 2, 1, cur); }
    READ_A(1, cur);
    __builtin_amdgcn_s_setprio(1);
    MFMA_Q(1, 1, b1);
    MFMA_Q(1, 0, b0);
    __builtin_amdgcn_s_setprio(0);
    if (T < 30) {
      VMW(4);
      BARR;
    } else if (T == 30) {
      VMW(0);          // tail: tile 31 must fully land (nothing issued behind it)
      BARR;
    }
  }

  // ---- epilogue: C/D col = lane&15 (N), row = quad*4+reg (M) ----
  #pragma unroll
  for (int nfg = 0; nfg < 4; ++nfg) {
    const int d = n0 + wn * 64 + nfg * 16 + l16;
    const float bv = bias[d];
    #pragma unroll
    for (int mfg = 0; mfg < 8; ++mfg) {
      const int lrow = l0 + wm * 128 + mfg * 16 + quad * 4;
      #pragma unroll
      for (int rg = 0; rg < 4; ++rg) {
        out[((size_t)(b * L_DIM + lrow + rg) * 4 + j) * D_DIM + d] = acc[mfg][nfg][rg] + bv;
      }
    }
  }
}

// ---------------- fallback: fused kernel (used if ws too small) ----------------
__global__ __launch_bounds__(256, 2) void fused_gemm(
    const unsigned short* __restrict__ XbfZ, const unsigned short* __restrict__ Ball,
    const float* __restrict__ W, const float* __restrict__ bias,
    float* __restrict__ out) {
  __shared__ alignas(16) unsigned short Vt[2][4096];
  __shared__ alignas(16) unsigned short Bt[2][8192];
  __shared__ alignas(16) unsigned short At[128 * 40];
  __shared__ alignas(16) unsigned short Wr[3 * 512];

  const int tid = threadIdx.x;
  const int nt = blockIdx.x & 1;
  const int mt = blockIdx.x >> 1;
  const int j  = mt >> 6;
  const int b  = (mt >> 4) & 3;
  const int lt = mt & 15;
  const int l0 = lt * 128;
  const int n0 = nt * 256;
  const int base_l = l0 - ((j == 3) ? 0 : 1);

  #pragma unroll
  for (int i = 0; i < 6; ++i) {
    const int idx = tid + i * 256;
    const int si = idx >> 9, c = idx & 511, s = 1 << si;
    Wr[idx] = (unsigned short)f2bf(W[j * 512 + ((c - s) & 511)]);
  }

  const int lane = tid & 63, wv = tid >> 6;
  const int qv = (lane & 3) ^ ((lane >> 4) & 3);
  const int rsub = lane >> 2;
  const unsigned short* gA0 = XbfZ + ((size_t)(b * NROWS_X + 1 + base_l + (wv * 2) * 16 + rsub)) * 512 + qv * 8;
  const unsigned short* gA1 = gA0 + (size_t)16 * 512;
  const unsigned short* gB[4];
  #pragma unroll
  for (int pi = 0; pi < 4; ++pi)
    gB[pi] = Ball + (size_t)(j * 512 + n0 + (wv * 4 + pi) * 16 + rsub) * KB_DIM + qv * 8;
  const int vOff0 = wv * 1024 + lane * 8;
  const int bOff0 = wv * 2048 + lane * 8;

  const int am = tid >> 1;
  const int akh = (tid & 1) * 16;
  const int ch0 = (tid & 1) * 2;
  const int sswz = (am >> 2) & 3;
  unsigned short* aDst = &At[am * 40 + akh];

  const int l16 = lane & 15, quad = lane >> 4;
  const int wm = wv >> 1, wn = wv & 1;
  const int fsw = (l16 >> 2) & 3;
  const int aVoff = (wm * 64 + l16) * 32 + ((quad ^ fsw)) * 8;
  const int aSoff = (wm * 64 + l16) * 40 + quad * 8;
  const int bOffF = (wn * 128 + l16) * 32 + ((quad ^ fsw)) * 8;

  f32x4 acc[4][8];
  #pragma unroll
  for (int i = 0; i < 4; ++i)
    #pragma unroll
    for (int n = 0; n < 8; ++n)
      acc[i][n] = f32x4{0.f, 0.f, 0.f, 0.f};

  {
    gld_lds16(gA0, &Vt[0][vOff0]);
    gld_lds16(gA1, &Vt[0][vOff0 + 512]);
    #pragma unroll
    for (int pi = 0; pi < 4; ++pi)
      gld_lds16(gB[pi], &Bt[0][bOff0 + pi * 512]);
  }

  for (int it = 0; it < 64; ++it) {
    const int buf = it & 1;
    const int kk0 = it * 32;
    const int gi = kk0 >> 9;

    __syncthreads();

    if (it + 1 < 64) {
      const int nk = kk0 + 32;
      const int nv = nk & 511;
      gld_lds16(gA0 + nv, &Vt[buf ^ 1][vOff0]);
      gld_lds16(gA1 + nv, &Vt[buf ^ 1][vOff0 + 512]);
      #pragma unroll
      for (int pi = 0; pi < 4; ++pi)
        gld_lds16(gB[pi] + nk, &Bt[buf ^ 1][bOff0 + pi * 512]);
    }

    bf16x8 af[4], bfr[8];
    if (gi == 0) {
      #pragma unroll
      for (int mi = 0; mi < 4; ++mi) {
        uint4 r = *reinterpret_cast<const uint4*>(&Vt[buf][aVoff + mi * 512]);
        af[mi] = __builtin_bit_cast(bf16x8, r);
      }
    } else {
      const int si = gi - 1;
      const int ccbase = (kk0 & 511) + akh;
      uint4 v0 = *reinterpret_cast<const uint4*>(&Vt[buf][(am * 4 + ((ch0)     ^ sswz)) * 8]);
      uint4 v1 = *reinterpret_cast<const uint4*>(&Vt[buf][(am * 4 + ((ch0 + 1) ^ sswz)) * 8]);
      uint4 w0 = *reinterpret_cast<const uint4*>(&Wr[si * 512 + ccbase]);
      uint4 w1 = *reinterpret_cast<const uint4*>(&Wr[si * 512 + ccbase + 8]);
      union U { uint4 q[2]; unsigned short s[16]; };
      U va, wa; va.q[0] = v0; va.q[1] = v1; wa.q[0] = w0; wa.q[1] = w1;
      unsigned res[8];
      #pragma unroll
      for (int e = 0; e < 8; ++e) {
        float s0 = bf2f(va.s[2 * e])     * bf2f(wa.s[2 * e]);
        float s1 = bf2f(va.s[2 * e + 1]) * bf2f(wa.s[2 * e + 1]);
        float g0 = s0 * __builtin_amdgcn_rcpf(1.f + __expf(-s0));
        float g1 = s1 * __builtin_amdgcn_rcpf(1.f + __expf(-s1));
        res[e] = f2bf(g0) | (f2bf(g1) << 16);
      }
      uint4 o0 = {res[0], res[1], res[2], res[3]};
      uint4 o1 = {res[4], res[5], res[6], res[7]};
      *reinterpret_cast<uint4*>(aDst) = o0;
      *reinterpret_cast<uint4*>(aDst + 8) = o1;
      __syncthreads();
      #pragma unroll
      for (int mi = 0; mi < 4; ++mi) {
        uint4 r = *reinterpret_cast<const uint4*>(&At[aSoff + mi * 640]);
        af[mi] = __builtin_bit_cast(bf16x8, r);
      }
    }
    #pragma unroll
    for (int ni = 0; ni < 8; ++ni) {
      uint4 r = *reinterpret_cast<const uint4*>(&Bt[buf][bOffF + ni * 512]);
      bfr[ni] = __builtin_bit_cast(bf16x8, r);
    }
    #pragma unroll
    for (int mi = 0; mi < 4; ++mi)
      #pragma unroll
      for (int ni = 0; ni < 8; ++ni)
        acc[mi][ni] = __builtin_amdgcn_mfma_f32_16x16x32_bf16(af[mi], bfr[ni], acc[mi][ni], 0, 0, 0);
  }

  #pragma unroll
  for (int ni = 0; ni < 8; ++ni) {
    const int d = n0 + wn * 128 + ni * 16 + l16;
    const float bv = bias[d];
    #pragma unroll
    for (int mi = 0; mi < 4; ++mi) {
      const int lrow = l0 + wm * 64 + mi * 16 + quad * 4;
      #pragma unroll
      for (int rg = 0; rg < 4; ++rg) {
        out[((size_t)(b * L_DIM + lrow + rg) * 4 + j) * D_DIM + d] = acc[mi][ni][rg] + bv;
      }
    }
  }
}

extern "C" void kernel_launch(void* const* d_in, const int* in_sizes, int n_in,
                              void* d_out, int out_size, void* d_ws, size_t ws_size,
                              hipStream_t stream) {
  const float* x    = (const float*)d_in[0];  // (4,1,2048,512) fp32
  const float* W    = (const float*)d_in[1];  // (4,512) fp32
  const float* P    = (const float*)d_in[2];  // (3072,512) fp32
  const float* bias = (const float*)d_in[3];  // (512,) fp32
  float* out = (float*)d_out;                 // (4,1,8192,512) fp32

  unsigned short* XbfZ = (unsigned short*)d_ws;                       // 4*2049*512   = 4,196,352 shorts
  unsigned short* Ball = XbfZ + (size_t)4 * NROWS_X * 512;            // 4*512*2048   = 4,194,304
  unsigned short* GS   = Ball + (size_t)4 * 512 * KB_DIM + 6144;      // 32768*1536   = 50,331,648
  const size_t need_bytes =
      ((size_t)4 * NROWS_X * 512 + (size_t)4 * 512 * KB_DIM + 6144 +
       (size_t)M_TOT * KS_DIM) * 2;
  const bool primary = ws_size >= need_bytes;

  prep<<<2304, 256, 0, stream>>>(x, W, P, XbfZ, Ball, GS, primary ? 1 : 0);
  if (primary) {
    gemm8<<<dim3(256), dim3(512), 0, stream>>>(XbfZ, GS, Ball, bias, out);
  } else {
    fused_gemm<<<512, 256, 0, stream>>>(XbfZ, Ball, W, bias, out);
  }
}